// Round 12
// baseline (175.462 us; speedup 1.0000x reference)
//
#include <hip/hip_runtime.h>
#include <hip/hip_bf16.h>

#define NTOT 8192   // 2B
#define BB   4096   // B
#define DD   256    // D
#define NBLK 512    // k_simsum blocks (2/CU)
#define NCHUNK 16640  // sum_{r<64} (512 - 8r)

typedef __attribute__((ext_vector_type(8))) short short8v;  // 8 bf16 = 4 VGPR
typedef __attribute__((ext_vector_type(4))) float f32x4;

__device__ __forceinline__ unsigned short f2bf(float f) {
    union { __hip_bfloat16 h; unsigned short u; } cv;
    cv.h = __float2bfloat16(f);
    return cv.u;
}

// One wave per pair r: normalize x1[r], x2[r]; emit bf16 z rows r and r+BB;
// fp32 selfdot (z.z) and posdot (z1.z2). Blocks 0-7 zero S; block 0 zeros out.
__global__ __launch_bounds__(256) void k_normalize(
    const float* __restrict__ x1, const float* __restrict__ x2,
    unsigned short* __restrict__ zbf,
    float* __restrict__ selfdot, float* __restrict__ posdot,
    float* __restrict__ S, float* __restrict__ out)
{
    if (blockIdx.x < 8) {
        float4 z4 = make_float4(0.f, 0.f, 0.f, 0.f);
        *(float4*)(S + blockIdx.x * 1024 + threadIdx.x * 4) = z4;
        if (blockIdx.x == 0 && threadIdx.x == 0) out[0] = 0.0f;
    }

    const int lane = threadIdx.x & 63;
    const int pair = blockIdx.x * 4 + (threadIdx.x >> 6);

    const float4 a = *(const float4*)(x1 + (size_t)pair * DD + lane * 4);
    const float4 b = *(const float4*)(x2 + (size_t)pair * DD + lane * 4);

    float s1 = a.x * a.x + a.y * a.y + a.z * a.z + a.w * a.w;
    float s2 = b.x * b.x + b.y * b.y + b.z * b.z + b.w * b.w;
#pragma unroll
    for (int off = 1; off < 64; off <<= 1) {
        s1 += __shfl_xor(s1, off);
        s2 += __shfl_xor(s2, off);
    }
    const float inv1 = 1.0f / fmaxf(sqrtf(s1), 1e-12f);
    const float inv2 = 1.0f / fmaxf(sqrtf(s2), 1e-12f);

    const float4 z1 = make_float4(a.x * inv1, a.y * inv1, a.z * inv1, a.w * inv1);
    const float4 z2 = make_float4(b.x * inv2, b.y * inv2, b.z * inv2, b.w * inv2);

    float sd1 = z1.x * z1.x + z1.y * z1.y + z1.z * z1.z + z1.w * z1.w;
    float sd2 = z2.x * z2.x + z2.y * z2.y + z2.z * z2.z + z2.w * z2.w;
    float pd  = z1.x * z2.x + z1.y * z2.y + z1.z * z2.z + z1.w * z2.w;
#pragma unroll
    for (int off = 1; off < 64; off <<= 1) {
        sd1 += __shfl_xor(sd1, off);
        sd2 += __shfl_xor(sd2, off);
        pd  += __shfl_xor(pd, off);
    }

    ushort4 u1, u2;
    u1.x = f2bf(z1.x); u1.y = f2bf(z1.y); u1.z = f2bf(z1.z); u1.w = f2bf(z1.w);
    u2.x = f2bf(z2.x); u2.y = f2bf(z2.y); u2.z = f2bf(z2.z); u2.w = f2bf(z2.w);
    *(ushort4*)(zbf + (size_t)pair * DD + lane * 4) = u1;
    *(ushort4*)(zbf + (size_t)(pair + BB) * DD + lane * 4) = u2;

    if (lane == 0) {
        selfdot[pair] = sd1;
        selfdot[pair + BB] = sd2;
        posdot[pair] = pd;
        posdot[pair + BB] = pd;
    }
}

// Round 12: SHARED-A / STREAMED-B triangle GEMM.
// Unifying theory of rounds 3-11: wall = staged-bytes / stream-rate.
//   R9/R11 (per-wave LDS dbuf): 265 MB @ 5.8 TB/s = 46 us (measured 46.8)
//   R3/R8 (block-shared + barriers): 134 MB but lockstep caps rate @2.4 TB/s
// Fix BOTH: A-tile (128 rows x 256 K = 64 KB, XOR-swizzled) staged ONCE per
// block via global_load_lds (pre-swizzled source, G21); B streamed DIRECTLY
// to VGPRs (64B-coalesced per-lane pattern proven in R7-R11 A-loads); 4
// waves free-run over 32-col units (2 chunks of 16 cols share each A-frag
// ds_read -> MFMA:ds_read = 2:1). Barriers ONLY at A-(re)stage (1-2/block).
// B traffic = 16640 chunks x 8 KB = 133 MB. Triangle: tile r (128 rows) has
// 512-8r chunks (first 8 = diagonal block, col-credit skipped); flat index
// P(r) = r(516-4r); block b owns chunks [65b/2, 65(b+1)/2) -> 32-33 each.
// Row sums in regs -> atomicAdd at tile end; col sums -> private colsum
// slots (R11 machinery), gathered in k_final.
__global__ __launch_bounds__(256, 2) void k_simsum(
    const unsigned short* __restrict__ zbf, float* __restrict__ S,
    float* __restrict__ colsum)
{
    __shared__ char Ash[65536];   // 128 rows x 512 B, swizzled

    const int tid  = threadIdx.x;
    const int lane = tid & 63;
    const int wv   = tid >> 6;
    const int frow = lane & 15;
    const int g    = lane >> 4;

    const int cBeg = (65 * blockIdx.x) >> 1;
    const int cEnd = (65 * (blockIdx.x + 1)) >> 1;

    // A ds_read addrs: row = rtg*16+frow; byte = row*512 + ((g*16+kk*64) ^
    // ((frow&7)<<4)); rtg*8192 added per use (all bit-disjoint, carry-free).
    int aoff[8];
#pragma unroll
    for (int kk = 0; kk < 8; ++kk)
        aoff[kk] = frow * 512 + ((g * 16 + kk * 64) ^ ((frow & 7) << 4));

    // A staging (G21): LDS dest linear tid*16 + q*4096; source pre-swizzled.
    const int srcBase = (tid >> 5) * 512
                      + (((tid & 31) << 4) ^ (((tid >> 5) & 7) << 4));

    // decode cBeg -> tile r, prefix P
    int r = 0, P = 0;
    while (P + 512 - 8 * r <= cBeg) { P += 512 - 8 * r; ++r; }

    float rs[8][4];
    int c = cBeg;
    bool first = true;

    while (c < cEnd) {
        const int tileEnd = P + 512 - 8 * r;
        const int segEnd = (cEnd < tileEnd) ? cEnd : tileEnd;

        if (!first) __syncthreads();   // all waves done reading old A
        // ---- stage A tile r (rows 128r..128r+127) ----
        {
            const char* asrc = (const char*)zbf + (size_t)r * 65536 + srcBase;
#pragma unroll
            for (int q = 0; q < 16; ++q)
                __builtin_amdgcn_global_load_lds(
                    (const __attribute__((address_space(1))) unsigned int*)(asrc + q * 4096),
                    (__attribute__((address_space(3))) unsigned int*)(&Ash[0] + tid * 16 + q * 4096),
                    16, 0, 0);
        }
        __syncthreads();               // staged A visible to all waves
        first = false;

#pragma unroll
        for (int rt = 0; rt < 8; ++rt)
#pragma unroll
            for (int q = 0; q < 4; ++q) rs[rt][q] = 0.0f;

        // ---- free-running pair loop (no barriers) ----
        const int segLen = segEnd - c;
        const int nPairs = (segLen + 1) >> 1;
        for (int j = wv; j < nPairs; j += 4) {
            const int c0 = c + 2 * j;
            const bool has1 = (c0 + 1 < segEnd);
            const float m1 = has1 ? 1.0f : 0.0f;
            const int t0 = c0 - P;
            const int colbase = r * 128 + 16 * t0;

            // B for both chunks -> VGPRs (64B-coalesced rows)
            const unsigned short* bp0 = zbf + (size_t)(colbase + frow) * DD + g * 8;
            const unsigned short* bp1 = zbf
                + (size_t)(colbase + (has1 ? 16 : 0) + frow) * DD + g * 8;
            short8v b0[8], b1[8];
#pragma unroll
            for (int kk = 0; kk < 8; ++kk) {
                b0[kk] = *(const short8v*)(bp0 + kk * 32);
                b1[kk] = *(const short8v*)(bp1 + kk * 32);
            }

            float cs0 = 0.0f, cs1 = 0.0f;
#pragma unroll
            for (int p = 0; p < 2; ++p) {   // rows p*64 .. p*64+63
                f32x4 acc[4][2];
#pragma unroll
                for (int rt = 0; rt < 4; ++rt)
#pragma unroll
                    for (int cc2 = 0; cc2 < 2; ++cc2) {
                        acc[rt][cc2][0] = 0.0f; acc[rt][cc2][1] = 0.0f;
                        acc[rt][cc2][2] = 0.0f; acc[rt][cc2][3] = 0.0f;
                    }
#pragma unroll
                for (int kk = 0; kk < 8; ++kk) {
#pragma unroll
                    for (int rt = 0; rt < 4; ++rt) {
                        const short8v a = *(const short8v*)(
                            &Ash[0] + (p * 4 + rt) * 8192 + aoff[kk]);
                        acc[rt][0] = __builtin_amdgcn_mfma_f32_16x16x32_bf16(
                            a, b0[kk], acc[rt][0], 0, 0, 0);
                        acc[rt][1] = __builtin_amdgcn_mfma_f32_16x16x32_bf16(
                            a, b1[kk], acc[rt][1], 0, 0, 0);
                    }
                }
                // epilogue: exp2(sim * 2/ln2), row + col accumulation
#pragma unroll
                for (int rt = 0; rt < 4; ++rt)
#pragma unroll
                    for (int q = 0; q < 4; ++q) {
                        const float e0 = exp2f(acc[rt][0][q] * 2.8853900817779268f);
                        const float e1 = exp2f(acc[rt][1][q] * 2.8853900817779268f);
                        rs[p * 4 + rt][q] += e0 + m1 * e1;
                        cs0 += e0; cs1 += e1;
                    }
            }
            // column sums over the 128 rows -> private slots (plain stores)
            cs0 += __shfl_xor(cs0, 16); cs0 += __shfl_xor(cs0, 32);
            cs1 += __shfl_xor(cs1, 16); cs1 += __shfl_xor(cs1, 32);
            if (lane < 16) {
                colsum[(size_t)c0 * 16 + frow] = cs0;
                if (has1) colsum[(size_t)(c0 + 1) * 16 + frow] = cs1;
            }
        }

        // ---- flush row sums for tile r (once per tile per wave) ----
#pragma unroll
        for (int rt = 0; rt < 8; ++rt)
#pragma unroll
            for (int q = 0; q < 4; ++q) {
                float val = rs[rt][q];
                val += __shfl_xor(val, 1);
                val += __shfl_xor(val, 2);
                val += __shfl_xor(val, 4);
                val += __shfl_xor(val, 8);
                if (frow == 0)
                    atomicAdd(&S[128 * r + rt * 16 + g * 4 + q], val);
            }

        c = segEnd;
        P = tileEnd;
        ++r;
    }
}

// 32 blocks x 256 threads: thread = one row. Row sum = S[i] (atomic flushes,
// covers cols >= 128*r_i incl. diagonal block) + col partials from tiles
// r < r_i: chunk (r, t=cc-8r), t>=8, flat sidx = r(516-4r) + (cc-8r).
__global__ __launch_bounds__(256) void k_final(
    const float* __restrict__ S, const float* __restrict__ colsum,
    const float* __restrict__ selfdot, const float* __restrict__ posdot,
    float* __restrict__ out)
{
    __shared__ float red[4];
    const int tid = threadIdx.x;
    const int i = blockIdx.x * 256 + tid;
    float s = S[i];
    const int cc = i >> 4, fr = i & 15;
    const int rEnd = i >> 7;
#pragma unroll 4
    for (int r = 0; r < rEnd; ++r) {
        const int sidx = r * (516 - 4 * r) + (cc - 8 * r);
        s += colsum[(size_t)sidx * 16 + fr];
    }
    const float den = fmaxf(s - expf(2.0f * selfdot[i]), 1e-8f);
    float acc = logf(den) - 2.0f * posdot[i];
#pragma unroll
    for (int off = 1; off < 64; off <<= 1) acc += __shfl_xor(acc, off);
    if ((tid & 63) == 0) red[tid >> 6] = acc;
    __syncthreads();
    if (tid == 0)
        atomicAdd(out, (red[0] + red[1] + red[2] + red[3]) * (1.0f / (float)NTOT));
}

extern "C" void kernel_launch(void* const* d_in, const int* in_sizes, int n_in,
                              void* d_out, int out_size, void* d_ws, size_t ws_size,
                              hipStream_t stream) {
    const float* x1 = (const float*)d_in[0];
    const float* x2 = (const float*)d_in[1];
    float* out = (float*)d_out;

    char* ws = (char*)d_ws;
    unsigned short* zbf = (unsigned short*)ws;                       // 4 MB
    size_t off = (size_t)NTOT * DD * sizeof(unsigned short);
    float* S = (float*)(ws + off);                                   // 32 KB
    off += (size_t)NTOT * sizeof(float);
    float* selfdot = (float*)(ws + off);                             // 32 KB
    off += (size_t)NTOT * sizeof(float);
    float* posdot = (float*)(ws + off);                              // 32 KB
    off += (size_t)NTOT * sizeof(float);
    float* colsum = (float*)(ws + off);                              // 1.07 MB

    k_normalize<<<dim3(BB / 4), dim3(256), 0, stream>>>(x1, x2, zbf, selfdot, posdot, S, out);
    k_simsum<<<dim3(NBLK), dim3(256), 0, stream>>>(zbf, S, colsum);
    k_final<<<dim3(NTOT / 256), dim3(256), 0, stream>>>(S, colsum, selfdot, posdot, out);
}